// Round 1
// baseline (4197.178 us; speedup 1.0000x reference)
//
#include <hip/hip_runtime.h>
#include <math.h>

// DNA-GNN: N=100000 nodes, E=3200000 edges, C=8, HEADS=2, d_head=4, 3 layers.
// glin with GROUPS=8, cin=cout=1 => per-channel scale+bias (no matmul).
//
// Workspace layout (floats):
//   xall : n*32   (per node: 4 layers x 8 ch, row = 128B, float4-aligned)
//   deg  : n      (becomes dinv in place)
//   agg  : n*8    (edge-aggregation accumulator, zeroed each use)

__global__ void init_kernel(float* __restrict__ deg, float* __restrict__ agg, int n) {
    int i = blockIdx.x * blockDim.x + threadIdx.x;
    if (i >= n) return;
    deg[i] = 1.0f;  // self-loop
    float4 z = make_float4(0.f, 0.f, 0.f, 0.f);
    float4* a = (float4*)(agg + (size_t)i * 8);
    a[0] = z; a[1] = z;
}

__global__ void count_deg(const int* __restrict__ eidx, float* __restrict__ deg, int E) {
    int e = blockIdx.x * blockDim.x + threadIdx.x;
    if (e < E) atomicAdd(&deg[eidx[E + e]], 1.0f);   // dst row of edge_index
}

__global__ void finish_deg(float* __restrict__ deg, int n) {
    int i = blockIdx.x * blockDim.x + threadIdx.x;
    if (i < n) deg[i] = rsqrtf(deg[i]);
}

// h0 = relu([emb_table[node_index], x] @ W1 + b1) -> xall layer 0
__global__ void node_init(const float* __restrict__ x, const int* __restrict__ nidx,
                          const float* __restrict__ emb, const float* __restrict__ W1,
                          const float* __restrict__ b1, float* __restrict__ xall, int n) {
    int i = blockIdx.x * blockDim.x + threadIdx.x;
    if (i >= n) return;
    float in[24];
    int ni = nidx[i];
    const float4* ep = (const float4*)(emb + (size_t)ni * 8);
    float4 e0 = ep[0], e1 = ep[1];
    in[0] = e0.x; in[1] = e0.y; in[2] = e0.z; in[3] = e0.w;
    in[4] = e1.x; in[5] = e1.y; in[6] = e1.z; in[7] = e1.w;
    const float4* xp = (const float4*)(x + (size_t)i * 16);
#pragma unroll
    for (int t = 0; t < 4; t++) {
        float4 v = xp[t];
        in[8 + 4 * t + 0] = v.x; in[8 + 4 * t + 1] = v.y;
        in[8 + 4 * t + 2] = v.z; in[8 + 4 * t + 3] = v.w;
    }
    float acc[8];
#pragma unroll
    for (int j = 0; j < 8; j++) acc[j] = b1[j];
#pragma unroll
    for (int t = 0; t < 24; t++) {
        float xv = in[t];
#pragma unroll
        for (int j = 0; j < 8; j++) acc[j] = fmaf(xv, W1[t * 8 + j], acc[j]);
    }
    float* o = xall + (size_t)i * 32;
#pragma unroll
    for (int j = 0; j < 8; j++) o[j] = fmaxf(acc[j], 0.0f);
}

// One thread per edge (incl. self-loops e >= E: src=dst=e-E).
template <int Li>
__global__ void edge_attn(const int* __restrict__ eidx, const float* __restrict__ xall,
                          const float* __restrict__ dinv,
                          const float* __restrict__ wq, const float* __restrict__ bq,
                          const float* __restrict__ wk, const float* __restrict__ bk,
                          const float* __restrict__ wv, const float* __restrict__ bv,
                          float* __restrict__ agg, int Etot, int E) {
    int e = blockIdx.x * blockDim.x + threadIdx.x;
    if (e >= Etot) return;
    int s, d;
    if (e < E) { s = eidx[e]; d = eidx[E + e]; }
    else       { s = d = e - E; }

    // q = x_all[dst, Li-1, :] * wq + bq
    const float4* qp = (const float4*)(xall + (size_t)d * 32 + (Li - 1) * 8);
    float4 q0 = qp[0], q1 = qp[1];
    float qv[8] = { q0.x, q0.y, q0.z, q0.w, q1.x, q1.y, q1.z, q1.w };
#pragma unroll
    for (int c = 0; c < 8; c++) qv[c] = fmaf(qv[c], wq[c], bq[c]);

    // raw x_all[src, 0..Li-1, :]
    float xs[8 * Li];
    const float4* sp = (const float4*)(xall + (size_t)s * 32);
#pragma unroll
    for (int t = 0; t < 2 * Li; t++) {
        float4 v = sp[t];
        xs[4 * t + 0] = v.x; xs[4 * t + 1] = v.y;
        xs[4 * t + 2] = v.z; xs[4 * t + 3] = v.w;
    }

    // scores: score[h][l] = 0.5 * sum_d q[h*4+d] * (xs[l*8+h*4+d]*wk+bk)
    float score[2][Li];
#pragma unroll
    for (int l = 0; l < Li; l++) {
#pragma unroll
        for (int h = 0; h < 2; h++) {
            float sc = 0.f;
#pragma unroll
            for (int dd = 0; dd < 4; dd++) {
                int c = h * 4 + dd;
                sc = fmaf(qv[c], fmaf(xs[l * 8 + c], wk[c], bk[c]), sc);
            }
            score[h][l] = 0.5f * sc;
        }
    }

    // softmax over l (per head)
    float attn[2][Li];
#pragma unroll
    for (int h = 0; h < 2; h++) {
        float m = score[h][0];
#pragma unroll
        for (int l = 1; l < Li; l++) m = fmaxf(m, score[h][l]);
        float ssum = 0.f;
#pragma unroll
        for (int l = 0; l < Li; l++) { attn[h][l] = __expf(score[h][l] - m); ssum += attn[h][l]; }
        float inv = 1.0f / ssum;
#pragma unroll
        for (int l = 0; l < Li; l++) attn[h][l] *= inv;
    }

    float nrm = dinv[s] * dinv[d];
    float* ag = agg + (size_t)d * 8;
#pragma unroll
    for (int c = 0; c < 8; c++) {
        int h = c >> 2;
        float o = 0.f;
#pragma unroll
        for (int l = 0; l < Li; l++) o = fmaf(attn[h][l], fmaf(xs[l * 8 + c], wv[c], bv[c]), o);
        atomicAdd(&ag[c], o * nrm);
    }
}

// relu(agg) -> xall layer `layer`, and re-zero agg for the next layer
__global__ void relu_store(float* __restrict__ agg, float* __restrict__ xall, int layer, int n) {
    int i = blockIdx.x * blockDim.x + threadIdx.x;
    if (i >= n) return;
    float* a = agg + (size_t)i * 8;
    float* o = xall + (size_t)i * 32 + layer * 8;
#pragma unroll
    for (int c = 0; c < 8; c++) { o[c] = fmaxf(a[c], 0.f); a[c] = 0.f; }
}

__global__ void classify(const float* __restrict__ xall, const float* __restrict__ W2,
                         const float* __restrict__ b2, float* __restrict__ out, int n) {
    int i = blockIdx.x * blockDim.x + threadIdx.x;
    if (i >= n) return;
    const float* h = xall + (size_t)i * 32 + 24;
    float z0 = b2[0], z1 = b2[1];
#pragma unroll
    for (int c = 0; c < 8; c++) {
        z0 = fmaf(h[c], W2[c * 2 + 0], z0);
        z1 = fmaf(h[c], W2[c * 2 + 1], z1);
    }
    float m = fmaxf(z0, z1);
    float lse = m + logf(__expf(z0 - m) + __expf(z1 - m));
    ((float2*)out)[i] = make_float2(z0 - lse, z1 - lse);
}

extern "C" void kernel_launch(void* const* d_in, const int* in_sizes, int n_in,
                              void* d_out, int out_size, void* d_ws, size_t ws_size,
                              hipStream_t stream) {
    const float* x    = (const float*)d_in[0];
    const int*   nidx = (const int*)d_in[1];
    const int*   eidx = (const int*)d_in[3];
    const float* emb  = (const float*)d_in[5];
    const float* W1   = (const float*)d_in[6];
    const float* b1   = (const float*)d_in[7];
    const float* Wq   = (const float*)d_in[8];
    const float* bq   = (const float*)d_in[9];
    const float* Wk   = (const float*)d_in[10];
    const float* bk   = (const float*)d_in[11];
    const float* Wv   = (const float*)d_in[12];
    const float* bv   = (const float*)d_in[13];
    const float* W2   = (const float*)d_in[14];
    const float* b2   = (const float*)d_in[15];
    float* out = (float*)d_out;

    const int n = in_sizes[0] / 16;       // 100000
    const int E = in_sizes[3] / 2;        // 3200000
    const int Etot = E + n;

    float* ws   = (float*)d_ws;
    float* xall = ws;                       // n*32
    float* deg  = ws + (size_t)n * 32;      // n (becomes dinv)
    float* agg  = ws + (size_t)n * 33;      // n*8

    dim3 blk(256);
    dim3 gn((n + 255) / 256), ge((E + 255) / 256), get((Etot + 255) / 256);

    init_kernel<<<gn, blk, 0, stream>>>(deg, agg, n);
    count_deg<<<ge, blk, 0, stream>>>(eidx, deg, E);
    finish_deg<<<gn, blk, 0, stream>>>(deg, n);
    node_init<<<gn, blk, 0, stream>>>(x, nidx, emb, W1, b1, xall, n);

    edge_attn<1><<<get, blk, 0, stream>>>(eidx, xall, deg, Wq, bq, Wk, bk, Wv, bv, agg, Etot, E);
    relu_store<<<gn, blk, 0, stream>>>(agg, xall, 1, n);
    edge_attn<2><<<get, blk, 0, stream>>>(eidx, xall, deg, Wq + 8, bq + 8, Wk + 8, bk + 8, Wv + 8, bv + 8, agg, Etot, E);
    relu_store<<<gn, blk, 0, stream>>>(agg, xall, 2, n);
    edge_attn<3><<<get, blk, 0, stream>>>(eidx, xall, deg, Wq + 16, bq + 16, Wk + 16, bk + 16, Wv + 16, bv + 16, agg, Etot, E);
    relu_store<<<gn, blk, 0, stream>>>(agg, xall, 3, n);

    classify<<<gn, blk, 0, stream>>>(xall, W2, b2, out, n);
}

// Round 2
// 651.285 us; speedup vs baseline: 6.4445x; 6.4445x over previous
//
#include <hip/hip_runtime.h>
#include <math.h>

// DNA-GNN: N=100000, E=3200000, C=8, HEADS=2, d_head=4, 3 layers.
// glin with GROUPS=8, cin=cout=1 => per-channel scale+bias.
//
// Strategy: CSR (edges grouped by dst, self-loop first in each segment),
// built once per call with int atomics; then per-layer dst-parallel gather
// aggregation with NO atomics (8 lanes per dst, shfl_xor reduce).
//
// Workspace (floats/ints), ~27.6 MB:
//   xall : n*32 f32   dinv : n f32   cnt : n i32   fill : n i32
//   off  : (n+1) i32  bsum : NB i32  ssrc: Etot i32

#define CHUNK 1024

__global__ void init_cnt(int* __restrict__ cnt, int n) {
    int i = blockIdx.x * blockDim.x + threadIdx.x;
    if (i < n) cnt[i] = 1;  // self-loop
}

__global__ void count_dst(const int* __restrict__ eidx, int* __restrict__ cnt, int E) {
    int e = blockIdx.x * blockDim.x + threadIdx.x;
    if (e < E) atomicAdd(&cnt[eidx[E + e]], 1);
}

// per-block sums of cnt (CHUNK elems per block)
__global__ void scanA(const int* __restrict__ cnt, int* __restrict__ bsum, int n) {
    __shared__ int sd[256];
    int t = threadIdx.x, b = blockIdx.x;
    int base = b * CHUNK + t * 4;
    int ts = 0;
#pragma unroll
    for (int k = 0; k < 4; k++) { int i = base + k; if (i < n) ts += cnt[i]; }
    sd[t] = ts; __syncthreads();
    for (int s = 128; s > 0; s >>= 1) { if (t < s) sd[t] += sd[t + s]; __syncthreads(); }
    if (t == 0) bsum[b] = sd[0];
}

// serial exclusive scan of block sums + write off[n]
__global__ void scanB(int* __restrict__ bsum, int* __restrict__ off, int NB, int n, int Etot) {
    int acc = 0;
    for (int b = 0; b < NB; b++) { int v = bsum[b]; bsum[b] = acc; acc += v; }
    off[n] = Etot;
}

// block-level exclusive scan -> off[i]; also dinv, fill=1, self-edge placement
__global__ void scanC(const int* __restrict__ cnt, const int* __restrict__ bsum,
                      int* __restrict__ off, float* __restrict__ dinv,
                      int* __restrict__ fill, int* __restrict__ ssrc, int n) {
    __shared__ int sd[256];
    int t = threadIdx.x, b = blockIdx.x;
    int base = b * CHUNK + t * 4;
    int c[4]; int ts = 0;
#pragma unroll
    for (int k = 0; k < 4; k++) { int i = base + k; c[k] = (i < n) ? cnt[i] : 0; ts += c[k]; }
    sd[t] = ts; __syncthreads();
    // Hillis-Steele inclusive scan over 256 thread sums
    for (int o = 1; o < 256; o <<= 1) {
        int v = 0; if (t >= o) v = sd[t - o];
        __syncthreads(); sd[t] += v; __syncthreads();
    }
    int toff = bsum[b] + sd[t] - ts;
#pragma unroll
    for (int k = 0; k < 4; k++) {
        int i = base + k;
        if (i < n) {
            off[i] = toff;
            dinv[i] = rsqrtf((float)c[k]);
            fill[i] = 1;          // slot 0 reserved for self-loop
            ssrc[toff] = i;       // self edge
            toff += c[k];
        }
    }
}

__global__ void fill_csr(const int* __restrict__ eidx, const int* __restrict__ off,
                         int* __restrict__ fill, int* __restrict__ ssrc, int E) {
    int e = blockIdx.x * blockDim.x + threadIdx.x;
    if (e >= E) return;
    int s = eidx[e], d = eidx[E + e];
    int pos = off[d] + atomicAdd(&fill[d], 1);
    ssrc[pos] = s;
}

// h0 = relu([emb_table[node_index], x] @ W1 + b1) -> xall layer 0
__global__ void node_init(const float* __restrict__ x, const int* __restrict__ nidx,
                          const float* __restrict__ emb, const float* __restrict__ W1,
                          const float* __restrict__ b1, float* __restrict__ xall, int n) {
    int i = blockIdx.x * blockDim.x + threadIdx.x;
    if (i >= n) return;
    float in[24];
    int ni = nidx[i];
    const float4* ep = (const float4*)(emb + (size_t)ni * 8);
    float4 e0 = ep[0], e1 = ep[1];
    in[0] = e0.x; in[1] = e0.y; in[2] = e0.z; in[3] = e0.w;
    in[4] = e1.x; in[5] = e1.y; in[6] = e1.z; in[7] = e1.w;
    const float4* xp = (const float4*)(x + (size_t)i * 16);
#pragma unroll
    for (int t = 0; t < 4; t++) {
        float4 v = xp[t];
        in[8 + 4 * t + 0] = v.x; in[8 + 4 * t + 1] = v.y;
        in[8 + 4 * t + 2] = v.z; in[8 + 4 * t + 3] = v.w;
    }
    float acc[8];
#pragma unroll
    for (int j = 0; j < 8; j++) acc[j] = b1[j];
#pragma unroll
    for (int t = 0; t < 24; t++) {
        float xv = in[t];
#pragma unroll
        for (int j = 0; j < 8; j++) acc[j] = fmaf(xv, W1[t * 8 + j], acc[j]);
    }
    float* o = xall + (size_t)i * 32;
#pragma unroll
    for (int j = 0; j < 8; j++) o[j] = fmaxf(acc[j], 0.0f);
}

// 8 lanes per dst node; lane t handles slots lo+t, lo+t+8, ...
// All atomic-free: accumulate in registers, shfl_xor reduce within 8-lane group.
template <int Li>
__global__ void agg_layer(const int* __restrict__ ssrc, const int* __restrict__ off,
                          const float* __restrict__ xall_in, float* __restrict__ xall,
                          const float* __restrict__ dinv,
                          const float* __restrict__ wq, const float* __restrict__ bq,
                          const float* __restrict__ wk, const float* __restrict__ bk,
                          const float* __restrict__ wv, const float* __restrict__ bv,
                          int n) {
    int tid = blockIdx.x * blockDim.x + threadIdx.x;
    int d = tid >> 3, t = tid & 7;
    if (d >= n) return;
    int lo = off[d], hi = off[d + 1];

    // q = x_all[dst, Li-1, :] * wq + bq  (same for all 8 lanes of the group)
    const float4* qp = (const float4*)(xall_in + (size_t)d * 32 + (Li - 1) * 8);
    float4 q0 = qp[0], q1 = qp[1];
    float qv[8] = { q0.x, q0.y, q0.z, q0.w, q1.x, q1.y, q1.z, q1.w };
#pragma unroll
    for (int c = 0; c < 8; c++) qv[c] = fmaf(qv[c], wq[c], bq[c]);

    float acc[8];
#pragma unroll
    for (int c = 0; c < 8; c++) acc[c] = 0.f;

    for (int slot = lo + t; slot < hi; slot += 8) {
        int s = ssrc[slot];
        float xs[8 * Li];
        const float4* sp = (const float4*)(xall_in + (size_t)s * 32);
#pragma unroll
        for (int u = 0; u < 2 * Li; u++) {
            float4 v = sp[u];
            xs[4 * u + 0] = v.x; xs[4 * u + 1] = v.y;
            xs[4 * u + 2] = v.z; xs[4 * u + 3] = v.w;
        }
        // scores
        float score[2][Li];
#pragma unroll
        for (int l = 0; l < Li; l++) {
#pragma unroll
            for (int h = 0; h < 2; h++) {
                float sc = 0.f;
#pragma unroll
                for (int dd = 0; dd < 4; dd++) {
                    int c = h * 4 + dd;
                    sc = fmaf(qv[c], fmaf(xs[l * 8 + c], wk[c], bk[c]), sc);
                }
                score[h][l] = 0.5f * sc;
            }
        }
        // softmax over l per head
        float attn[2][Li];
#pragma unroll
        for (int h = 0; h < 2; h++) {
            float m = score[h][0];
#pragma unroll
            for (int l = 1; l < Li; l++) m = fmaxf(m, score[h][l]);
            float ssum = 0.f;
#pragma unroll
            for (int l = 0; l < Li; l++) { attn[h][l] = __expf(score[h][l] - m); ssum += attn[h][l]; }
            float inv = 1.0f / ssum;
#pragma unroll
            for (int l = 0; l < Li; l++) attn[h][l] *= inv;
        }
        float ns = dinv[s];
#pragma unroll
        for (int c = 0; c < 8; c++) {
            int h = c >> 2;
            float o = 0.f;
#pragma unroll
            for (int l = 0; l < Li; l++) o = fmaf(attn[h][l], fmaf(xs[l * 8 + c], wv[c], bv[c]), o);
            acc[c] += o * ns;
        }
    }
    // reduce across the 8 lanes of this dst group
#pragma unroll
    for (int m = 1; m < 8; m <<= 1) {
#pragma unroll
        for (int c = 0; c < 8; c++) acc[c] += __shfl_xor(acc[c], m);
    }
    // lane t writes channel t (all lanes hold the full sum)
    float nd = dinv[d];
    xall[(size_t)d * 32 + Li * 8 + t] = fmaxf(acc[t] * nd, 0.f);
}

__global__ void classify(const float* __restrict__ xall, const float* __restrict__ W2,
                         const float* __restrict__ b2, float* __restrict__ out, int n) {
    int i = blockIdx.x * blockDim.x + threadIdx.x;
    if (i >= n) return;
    const float* h = xall + (size_t)i * 32 + 24;
    float z0 = b2[0], z1 = b2[1];
#pragma unroll
    for (int c = 0; c < 8; c++) {
        z0 = fmaf(h[c], W2[c * 2 + 0], z0);
        z1 = fmaf(h[c], W2[c * 2 + 1], z1);
    }
    float m = fmaxf(z0, z1);
    float lse = m + logf(__expf(z0 - m) + __expf(z1 - m));
    ((float2*)out)[i] = make_float2(z0 - lse, z1 - lse);
}

extern "C" void kernel_launch(void* const* d_in, const int* in_sizes, int n_in,
                              void* d_out, int out_size, void* d_ws, size_t ws_size,
                              hipStream_t stream) {
    const float* x    = (const float*)d_in[0];
    const int*   nidx = (const int*)d_in[1];
    const int*   eidx = (const int*)d_in[3];
    const float* emb  = (const float*)d_in[5];
    const float* W1   = (const float*)d_in[6];
    const float* b1   = (const float*)d_in[7];
    const float* Wq   = (const float*)d_in[8];
    const float* bq   = (const float*)d_in[9];
    const float* Wk   = (const float*)d_in[10];
    const float* bk   = (const float*)d_in[11];
    const float* Wv   = (const float*)d_in[12];
    const float* bv   = (const float*)d_in[13];
    const float* W2   = (const float*)d_in[14];
    const float* b2   = (const float*)d_in[15];
    float* out = (float*)d_out;

    const int n = in_sizes[0] / 16;       // 100000
    const int E = in_sizes[3] / 2;        // 3200000
    const int Etot = E + n;
    const int NB = (n + CHUNK - 1) / CHUNK;

    char* ws = (char*)d_ws;
    float* xall = (float*)ws;                       ws += (size_t)n * 32 * 4;
    float* dinv = (float*)ws;                       ws += (size_t)n * 4;
    int*   cnt  = (int*)ws;                         ws += (size_t)n * 4;
    int*   fill = (int*)ws;                         ws += (size_t)n * 4;
    int*   off  = (int*)ws;                         ws += (size_t)(n + 1) * 4;
    int*   bsum = (int*)ws;                         ws += (size_t)(NB + 4) * 4;
    int*   ssrc = (int*)ws;                         /* Etot ints */

    dim3 blk(256);
    dim3 gn((n + 255) / 256), ge((E + 255) / 256);
    dim3 ga((n * 8 + 255) / 256);

    init_cnt<<<gn, blk, 0, stream>>>(cnt, n);
    count_dst<<<ge, blk, 0, stream>>>(eidx, cnt, E);
    scanA<<<NB, blk, 0, stream>>>(cnt, bsum, n);
    scanB<<<1, 1, 0, stream>>>(bsum, off, NB, n, Etot);
    scanC<<<NB, blk, 0, stream>>>(cnt, bsum, off, dinv, fill, ssrc, n);
    fill_csr<<<ge, blk, 0, stream>>>(eidx, off, fill, ssrc, E);
    node_init<<<gn, blk, 0, stream>>>(x, nidx, emb, W1, b1, xall, n);

    agg_layer<1><<<ga, blk, 0, stream>>>(ssrc, off, xall, xall, dinv, Wq, bq, Wk, bk, Wv, bv, n);
    agg_layer<2><<<ga, blk, 0, stream>>>(ssrc, off, xall, xall, dinv, Wq + 8, bq + 8, Wk + 8, bk + 8, Wv + 8, bv + 8, n);
    agg_layer<3><<<ga, blk, 0, stream>>>(ssrc, off, xall, xall, dinv, Wq + 16, bq + 16, Wk + 16, bk + 16, Wv + 16, bv + 16, n);

    classify<<<gn, blk, 0, stream>>>(xall, W2, b2, out, n);
}